// Round 1
// baseline (705.260 us; speedup 1.0000x reference)
//
#include <hip/hip_runtime.h>
#include <hip/hip_bf16.h>

#define N_NODES 100000
#define N_EDGES 1600000
#define F_IN 128
#define HID 64
#define NC 10

// ---------------- degree histogram (edges only; +1 self-loop added in k_dis)
__global__ void k_deg(const int* __restrict__ dst, unsigned* __restrict__ deg) {
    int i = blockIdx.x * blockDim.x + threadIdx.x;
    int stride = gridDim.x * blockDim.x;
    for (; i < N_EDGES; i += stride)
        atomicAdd(&deg[dst[i]], 1u);
}

__global__ void k_dis(const unsigned* __restrict__ deg, float* __restrict__ dis) {
    int i = blockIdx.x * blockDim.x + threadIdx.x;
    if (i < N_NODES) dis[i] = rsqrtf((float)(deg[i] + 1u));
}

// ---------------- hx = x @ W1   (100000x128 @ 128x64), W1 in LDS
__global__ __launch_bounds__(256) void k_xw(const float* __restrict__ x,
                                            const float* __restrict__ W1,
                                            float* __restrict__ hx) {
    __shared__ float Ws[F_IN * HID];  // 32 KB
    for (int i = threadIdx.x; i < F_IN * HID; i += 256) Ws[i] = W1[i];
    __syncthreads();
    int lane = threadIdx.x & 63;   // output column
    int rg   = threadIdx.x >> 6;   // 0..3 row within block
    int n    = blockIdx.x * 4 + rg;
    if (n >= N_NODES) return;
    const float* xr = x + (size_t)n * F_IN;
    float acc = 0.f;
#pragma unroll 8
    for (int k = 0; k < F_IN; ++k)
        acc += xr[k] * Ws[k * HID + lane];
    hx[(size_t)n * HID + lane] = acc;
}

// ---------------- h1[n] = hx[n] * dis[n]^2  (self-loop message == init)
__global__ void k_self64(const float* __restrict__ hx, const float* __restrict__ dis,
                         float* __restrict__ h1) {
    size_t i = (size_t)blockIdx.x * blockDim.x + threadIdx.x;
    size_t total = (size_t)N_NODES * HID;
    size_t stride = (size_t)gridDim.x * blockDim.x;
    for (; i < total; i += stride) {
        int n = (int)(i >> 6);
        float d = dis[n];
        h1[i] = hx[i] * d * d;
    }
}

// ---------------- edge scatter, layer 1: one wave per edge, lane = col
__global__ __launch_bounds__(256) void k_scat1(const int* __restrict__ src,
                                               const int* __restrict__ dst,
                                               const float* __restrict__ dis,
                                               const float* __restrict__ hx,
                                               float* __restrict__ h1) {
    int lane = threadIdx.x & 63;
    int wave = (blockIdx.x * blockDim.x + threadIdx.x) >> 6;
    int nwaves = (gridDim.x * blockDim.x) >> 6;
    for (int e = wave; e < N_EDGES; e += nwaves) {
        int s = src[e], d = dst[e];
        float norm = dis[s] * dis[d];
        float v = hx[(size_t)s * HID + lane] * norm;
        atomicAdd(&h1[(size_t)d * HID + lane], v);
    }
}

// ---------------- h2x = relu(h1 + b1) @ W2  (fused bias+relu+GEMM)
__global__ __launch_bounds__(256) void k_h2x(const float* __restrict__ h1,
                                             const float* __restrict__ b1,
                                             const float* __restrict__ W2,
                                             float* __restrict__ h2x) {
    __shared__ float W2s[HID * NC];
    __shared__ float b1s[HID];
    for (int i = threadIdx.x; i < HID * NC; i += 256) W2s[i] = W2[i];
    if (threadIdx.x < HID) b1s[threadIdx.x] = b1[threadIdx.x];
    __syncthreads();
    int c  = threadIdx.x & 15;   // 16 lanes per row, 10 active
    int rg = threadIdx.x >> 4;   // 16 rows per block
    int n  = blockIdx.x * 16 + rg;
    if (n >= N_NODES || c >= NC) return;
    const float* hr = h1 + (size_t)n * HID;
    float acc = 0.f;
#pragma unroll
    for (int k = 0; k < HID; ++k) {
        float v = hr[k] + b1s[k];
        v = v > 0.f ? v : 0.f;
        acc += v * W2s[k * NC + c];
    }
    h2x[(size_t)n * NC + c] = acc;
}

// ---------------- agg2[n] = h2x[n] * dis[n]^2
__global__ void k_self10(const float* __restrict__ h2x, const float* __restrict__ dis,
                         float* __restrict__ agg2) {
    int i = blockIdx.x * blockDim.x + threadIdx.x;
    int total = N_NODES * NC;
    int stride = gridDim.x * blockDim.x;
    for (; i < total; i += stride) {
        int n = i / NC;
        float d = dis[n];
        agg2[i] = h2x[i] * d * d;
    }
}

// ---------------- edge scatter, layer 2: 16 lanes per edge, 10 active
__global__ __launch_bounds__(256) void k_scat2(const int* __restrict__ src,
                                               const int* __restrict__ dst,
                                               const float* __restrict__ dis,
                                               const float* __restrict__ h2x,
                                               float* __restrict__ agg2) {
    int sub = threadIdx.x & 15;
    int eg  = (blockIdx.x * blockDim.x + threadIdx.x) >> 4;
    int nes = (gridDim.x * blockDim.x) >> 4;
    for (int e = eg; e < N_EDGES; e += nes) {
        int s = src[e], d = dst[e];
        float norm = dis[s] * dis[d];
        if (sub < NC) {
            float v = h2x[(size_t)s * NC + sub] * norm;
            atomicAdd(&agg2[(size_t)d * NC + sub], v);
        }
    }
}

// ---------------- out = log_softmax(agg2 + b2), one thread per row
__global__ void k_final(const float* __restrict__ agg2, const float* __restrict__ b2,
                        float* __restrict__ out) {
    int n = blockIdx.x * blockDim.x + threadIdx.x;
    int stride = gridDim.x * blockDim.x;
    for (; n < N_NODES; n += stride) {
        float v[NC];
        float m = -1e30f;
#pragma unroll
        for (int c = 0; c < NC; ++c) {
            v[c] = agg2[n * NC + c] + b2[c];
            m = fmaxf(m, v[c]);
        }
        float s = 0.f;
#pragma unroll
        for (int c = 0; c < NC; ++c) s += expf(v[c] - m);
        float lse = m + logf(s);
#pragma unroll
        for (int c = 0; c < NC; ++c) out[n * NC + c] = v[c] - lse;
    }
}

extern "C" void kernel_launch(void* const* d_in, const int* in_sizes, int n_in,
                              void* d_out, int out_size, void* d_ws, size_t ws_size,
                              hipStream_t stream) {
    const float* x  = (const float*)d_in[0];
    const int*   ei = (const int*)d_in[1];    // [2, E] int32 (JAX x64 off)
    const float* W1 = (const float*)d_in[2];
    const float* b1 = (const float*)d_in[3];
    const float* W2 = (const float*)d_in[4];
    const float* b2 = (const float*)d_in[5];
    float* out = (float*)d_out;

    const int* src = ei;             // edge_index[0]
    const int* dst = ei + N_EDGES;   // edge_index[1]

    char* ws = (char*)d_ws;
    unsigned* deg = (unsigned*)ws;                               // N*4
    float* dis = (float*)(ws + 4u * N_NODES);                    // N*4
    float* hx  = (float*)(ws + 8u * N_NODES);                    // N*64*4 = 25.6 MB
    float* h1  = (float*)(ws + 8u * N_NODES + 4u * N_NODES * HID); // 25.6 MB
    // hx region is dead after k_scat1 -> alias layer-2 buffers onto it
    float* h2x  = hx;                                            // N*10*4 = 4 MB
    float* agg2 = hx + (size_t)N_NODES * NC;                     // 4 MB

    hipMemsetAsync(deg, 0, 4u * N_NODES, stream);
    k_deg<<<2048, 256, 0, stream>>>(dst, deg);
    k_dis<<<(N_NODES + 255) / 256, 256, 0, stream>>>(deg, dis);
    k_xw<<<(N_NODES + 3) / 4, 256, 0, stream>>>(x, W1, hx);
    k_self64<<<4096, 256, 0, stream>>>(hx, dis, h1);
    k_scat1<<<4096, 256, 0, stream>>>(src, dst, dis, hx, h1);
    k_h2x<<<(N_NODES + 15) / 16, 256, 0, stream>>>(h1, b1, W2, h2x);
    k_self10<<<2048, 256, 0, stream>>>(h2x, dis, agg2);
    k_scat2<<<4096, 256, 0, stream>>>(src, dst, dis, h2x, agg2);
    k_final<<<2048, 256, 0, stream>>>(agg2, b2, out);
}

// Round 2
// 702.551 us; speedup vs baseline: 1.0039x; 1.0039x over previous
//
#include <hip/hip_runtime.h>
#include <hip/hip_bf16.h>

#define N_NODES 100000
#define N_EDGES 1600000
#define F_IN 128
#define HID 64
#define NC 10
#define SCAN_T 1024

// ---------------- degree histogram (edges only; +1 self-loop added in k_dis)
__global__ void k_deg(const int* __restrict__ dst, unsigned* __restrict__ deg) {
    int i = blockIdx.x * blockDim.x + threadIdx.x;
    int stride = gridDim.x * blockDim.x;
    for (; i < N_EDGES; i += stride)
        atomicAdd(&deg[dst[i]], 1u);
}

__global__ void k_dis(const unsigned* __restrict__ deg, float* __restrict__ dis) {
    int i = blockIdx.x * blockDim.x + threadIdx.x;
    if (i < N_NODES) dis[i] = rsqrtf((float)(deg[i] + 1u));
}

// ---------------- exclusive prefix scan of deg -> row_start, cursor (1 block)
__global__ __launch_bounds__(SCAN_T) void k_scan(const unsigned* __restrict__ deg,
                                                 int* __restrict__ row_start,
                                                 int* __restrict__ cursor) {
    __shared__ int sums[SCAN_T];
    int t = threadIdx.x;
    const int chunk = (N_NODES + SCAN_T - 1) / SCAN_T;  // 98
    int beg = t * chunk;
    int end = beg + chunk < N_NODES ? beg + chunk : N_NODES;
    int local = 0;
    for (int i = beg; i < end; ++i) local += (int)deg[i];
    sums[t] = local;
    __syncthreads();
    for (int off = 1; off < SCAN_T; off <<= 1) {
        int v = (t >= off) ? sums[t - off] : 0;
        __syncthreads();
        sums[t] += v;
        __syncthreads();
    }
    int run = (t == 0) ? 0 : sums[t - 1];
    for (int i = beg; i < end; ++i) {
        int d = (int)deg[i];
        row_start[i] = run;
        cursor[i] = run;
        run += d;
    }
    if (t == SCAN_T - 1) row_start[N_NODES] = run;  // == N_EDGES
}

// ---------------- counting-sort scatter: csr[slot] = src, grouped by dst
__global__ void k_fill(const int* __restrict__ src, const int* __restrict__ dst,
                       int* __restrict__ cursor, int* __restrict__ csr) {
    int i = blockIdx.x * blockDim.x + threadIdx.x;
    int stride = gridDim.x * blockDim.x;
    for (; i < N_EDGES; i += stride) {
        int d = dst[i];
        int slot = atomicAdd(&cursor[d], 1);
        csr[slot] = src[i];
    }
}

// ---------------- hxs = (x @ W1) * dis[n]   (pre-scaled by D^-1/2)
__global__ __launch_bounds__(256) void k_xw(const float* __restrict__ x,
                                            const float* __restrict__ W1,
                                            const float* __restrict__ dis,
                                            float* __restrict__ hxs) {
    __shared__ float Ws[F_IN * HID];  // 32 KB
    for (int i = threadIdx.x; i < F_IN * HID; i += 256) Ws[i] = W1[i];
    __syncthreads();
    int lane = threadIdx.x & 63;   // output column
    int rg   = threadIdx.x >> 6;   // 0..3 row within block
    int n    = blockIdx.x * 4 + rg;
    if (n >= N_NODES) return;
    const float* xr = x + (size_t)n * F_IN;
    float acc = 0.f;
#pragma unroll 8
    for (int k = 0; k < F_IN; ++k)
        acc += xr[k] * Ws[k * HID + lane];
    hxs[(size_t)n * HID + lane] = acc * dis[n];
}

// ---------------- layer-1 aggregate: gather over CSR, one wave per node
// h1[n] = dis[n] * (hxs[n] + sum_{s in in(n)} hxs[s])
__global__ __launch_bounds__(256) void k_agg1(const int* __restrict__ row_start,
                                              const int* __restrict__ csr,
                                              const float* __restrict__ dis,
                                              const float* __restrict__ hxs,
                                              float* __restrict__ h1) {
    int lane = threadIdx.x & 63;
    int node = (blockIdx.x * blockDim.x + threadIdx.x) >> 6;
    if (node >= N_NODES) return;
    int beg = row_start[node], end = row_start[node + 1];
    float acc = hxs[(size_t)node * HID + lane];
    int j = beg;
    for (; j + 4 <= end; j += 4) {
        int s0 = csr[j], s1 = csr[j + 1], s2 = csr[j + 2], s3 = csr[j + 3];
        acc += hxs[(size_t)s0 * HID + lane];
        acc += hxs[(size_t)s1 * HID + lane];
        acc += hxs[(size_t)s2 * HID + lane];
        acc += hxs[(size_t)s3 * HID + lane];
    }
    for (; j < end; ++j)
        acc += hxs[(size_t)csr[j] * HID + lane];
    h1[(size_t)node * HID + lane] = acc * dis[node];
}

// ---------------- h2s = (relu(h1 + b1) @ W2) * dis[n]
__global__ __launch_bounds__(256) void k_h2x(const float* __restrict__ h1,
                                             const float* __restrict__ b1,
                                             const float* __restrict__ W2,
                                             const float* __restrict__ dis,
                                             float* __restrict__ h2s) {
    __shared__ float W2s[HID * NC];
    __shared__ float b1s[HID];
    for (int i = threadIdx.x; i < HID * NC; i += 256) W2s[i] = W2[i];
    if (threadIdx.x < HID) b1s[threadIdx.x] = b1[threadIdx.x];
    __syncthreads();
    int c  = threadIdx.x & 15;   // 16 lanes per row, 10 active
    int rg = threadIdx.x >> 4;   // 16 rows per block
    int n  = blockIdx.x * 16 + rg;
    if (n >= N_NODES || c >= NC) return;
    const float* hr = h1 + (size_t)n * HID;
    float acc = 0.f;
#pragma unroll
    for (int k = 0; k < HID; ++k) {
        float v = hr[k] + b1s[k];
        v = v > 0.f ? v : 0.f;
        acc += v * W2s[k * NC + c];
    }
    h2s[(size_t)n * NC + c] = acc * dis[n];
}

// ---------------- layer-2 aggregate + bias + log_softmax, fused
// pre[c] = dis[n]*(h2s[n][c] + sum h2s[s][c]) + b2[c]; out = pre - lse
__global__ __launch_bounds__(256) void k_agg2f(const int* __restrict__ row_start,
                                               const int* __restrict__ csr,
                                               const float* __restrict__ dis,
                                               const float* __restrict__ h2s,
                                               const float* __restrict__ b2,
                                               float* __restrict__ out) {
    int c = threadIdx.x & 15;  // 16 lanes per node, 10 active
    int node = (blockIdx.x * blockDim.x + threadIdx.x) >> 4;
    if (node >= N_NODES) return;
    int beg = row_start[node], end = row_start[node + 1];
    float acc;
    if (c < NC) {
        acc = h2s[(size_t)node * NC + c];
        int j = beg;
        for (; j + 2 <= end; j += 2) {
            int s0 = csr[j], s1 = csr[j + 1];
            acc += h2s[(size_t)s0 * NC + c];
            acc += h2s[(size_t)s1 * NC + c];
        }
        for (; j < end; ++j)
            acc += h2s[(size_t)csr[j] * NC + c];
        acc = acc * dis[node] + b2[c];
    } else {
        acc = -1e30f;
    }
    float m = acc;
#pragma unroll
    for (int off = 8; off >= 1; off >>= 1)
        m = fmaxf(m, __shfl_xor(m, off, 16));
    float e = (c < NC) ? expf(acc - m) : 0.f;
    float ssum = e;
#pragma unroll
    for (int off = 8; off >= 1; off >>= 1)
        ssum += __shfl_xor(ssum, off, 16);
    float lse = m + logf(ssum);
    if (c < NC) out[(size_t)node * NC + c] = acc - lse;
}

extern "C" void kernel_launch(void* const* d_in, const int* in_sizes, int n_in,
                              void* d_out, int out_size, void* d_ws, size_t ws_size,
                              hipStream_t stream) {
    const float* x  = (const float*)d_in[0];
    const int*   ei = (const int*)d_in[1];    // [2, E] int32 (JAX x64 off)
    const float* W1 = (const float*)d_in[2];
    const float* b1 = (const float*)d_in[3];
    const float* W2 = (const float*)d_in[4];
    const float* b2 = (const float*)d_in[5];
    float* out = (float*)d_out;

    const int* src = ei;             // edge_index[0]
    const int* dst = ei + N_EDGES;   // edge_index[1]

    char* ws = (char*)d_ws;
    size_t off = 0;
    unsigned* deg = (unsigned*)(ws + off); off += 4u * N_NODES;          // 0.4 MB
    float* dis = (float*)(ws + off);       off += 4u * N_NODES;          // 0.4 MB
    int* row_start = (int*)(ws + off);     off += 4u * (N_NODES + 4);    // 0.4 MB
    int* cursor = (int*)(ws + off);        off += 4u * N_NODES;          // 0.4 MB
    int* csr = (int*)(ws + off);           off += 4u * N_EDGES;          // 6.4 MB
    float* hxs = (float*)(ws + off);       off += 4u * N_NODES * HID;    // 25.6 MB
    float* h1  = (float*)(ws + off);       off += 4u * N_NODES * HID;    // 25.6 MB
    float* h2s = hxs;  // hxs dead after k_agg1; reuse region (4 MB)

    hipMemsetAsync(deg, 0, 4u * N_NODES, stream);
    k_deg<<<2048, 256, 0, stream>>>(dst, deg);
    k_dis<<<(N_NODES + 255) / 256, 256, 0, stream>>>(deg, dis);
    k_scan<<<1, SCAN_T, 0, stream>>>(deg, row_start, cursor);
    k_fill<<<2048, 256, 0, stream>>>(src, dst, cursor, csr);
    k_xw<<<(N_NODES + 3) / 4, 256, 0, stream>>>(x, W1, dis, hxs);
    k_agg1<<<(N_NODES * 64) / 256, 256, 0, stream>>>(row_start, csr, dis, hxs, h1);
    k_h2x<<<(N_NODES + 15) / 16, 256, 0, stream>>>(h1, b1, W2, dis, h2s);
    k_agg2f<<<(N_NODES * 16) / 256, 256, 0, stream>>>(row_start, csr, dis, h2s, b2, out);
}

// Round 3
// 399.982 us; speedup vs baseline: 1.7632x; 1.7565x over previous
//
#include <hip/hip_runtime.h>
#include <hip/hip_bf16.h>

#define N_NODES 100000
#define N_EDGES 1600000
#define F_IN 128
#define HID 64
#define NC 10
#define RED_B 256
#define CHUNK 391  // ceil(100000/256)

// ---------------- degree histogram (edges only; +1 self-loop later)
__global__ void k_deg(const int* __restrict__ dst, unsigned* __restrict__ deg) {
    int i = blockIdx.x * blockDim.x + threadIdx.x;
    int stride = gridDim.x * blockDim.x;
    for (; i < N_EDGES; i += stride)
        atomicAdd(&deg[dst[i]], 1u);
}

// ---------------- scan phase 1: per-block partial sums (coalesced)
__global__ __launch_bounds__(256) void k_red(const unsigned* __restrict__ deg,
                                             int* __restrict__ bsum) {
    int b = blockIdx.x;
    int beg = b * CHUNK;
    int end = beg + CHUNK < N_NODES ? beg + CHUNK : N_NODES;
    int s = 0;
    for (int i = beg + threadIdx.x; i < end; i += 256) s += (int)deg[i];
    __shared__ int sm[256];
    sm[threadIdx.x] = s;
    __syncthreads();
    for (int off = 128; off >= 1; off >>= 1) {
        if (threadIdx.x < off) sm[threadIdx.x] += sm[threadIdx.x + off];
        __syncthreads();
    }
    if (threadIdx.x == 0) bsum[b] = sm[0];
}

// ---------------- scan phase 2: exclusive scan of 256 block sums (1 block)
__global__ __launch_bounds__(256) void k_mid(const int* __restrict__ bsum,
                                             int* __restrict__ boff) {
    __shared__ int sm[256];
    int t = threadIdx.x;
    sm[t] = bsum[t];
    __syncthreads();
    for (int off = 1; off < 256; off <<= 1) {
        int u = (t >= off) ? sm[t - off] : 0;
        __syncthreads();
        sm[t] += u;
        __syncthreads();
    }
    boff[t] = (t == 0) ? 0 : sm[t - 1];
}

// ---------------- scan phase 3: rescan chunk, emit row_start/cursor/dis
__global__ __launch_bounds__(256) void k_fin(const unsigned* __restrict__ deg,
                                             const int* __restrict__ boff,
                                             int* __restrict__ row_start,
                                             int* __restrict__ cursor,
                                             float* __restrict__ dis) {
    __shared__ int sm[256];
    int b = blockIdx.x, t = threadIdx.x;
    int beg = b * CHUNK;
    int end = beg + CHUNK < N_NODES ? beg + CHUNK : N_NODES;
    int carry = boff[b];
    for (int tbeg = beg; tbeg < end; tbeg += 256) {
        int i = tbeg + t;
        int v = (i < end) ? (int)deg[i] : 0;
        sm[t] = v;
        __syncthreads();
        for (int off = 1; off < 256; off <<= 1) {
            int u = (t >= off) ? sm[t - off] : 0;
            __syncthreads();
            sm[t] += u;
            __syncthreads();
        }
        int excl = sm[t] - v;
        if (i < end) {
            int rs = carry + excl;
            row_start[i] = rs;
            cursor[i] = rs;
            dis[i] = rsqrtf((float)(deg[i] + 1u));
        }
        int tileTotal = sm[255];
        __syncthreads();  // everyone done reading sm before next tile overwrites
        carry += tileTotal;
    }
    if (b == RED_B - 1 && t == 0) row_start[N_NODES] = carry;  // == N_EDGES
}

// ---------------- counting-sort scatter: csr[slot] = src, grouped by dst
__global__ void k_fill(const int* __restrict__ src, const int* __restrict__ dst,
                       int* __restrict__ cursor, int* __restrict__ csr) {
    int i = blockIdx.x * blockDim.x + threadIdx.x;
    int stride = gridDim.x * blockDim.x;
    for (; i < N_EDGES; i += stride) {
        int d = dst[i];
        int slot = atomicAdd(&cursor[d], 1);
        csr[slot] = src[i];
    }
}

// ---------------- hxs = (x @ W1) * dis ; 8 nodes per wave, x via scalar loads
__global__ __launch_bounds__(256) void k_xw(const float* __restrict__ x,
                                            const float* __restrict__ W1,
                                            const float* __restrict__ dis,
                                            float* __restrict__ hxs) {
    __shared__ float Ws[F_IN * HID];  // 32 KB
    for (int i = threadIdx.x; i < F_IN * HID; i += 256) Ws[i] = W1[i];
    __syncthreads();
    int lane = threadIdx.x & 63;
    int wv = __builtin_amdgcn_readfirstlane(threadIdx.x >> 6);  // wave-uniform
    int base = (blockIdx.x * 4 + wv) * 8;  // 8 nodes per wave, 32 per block
    if (base >= N_NODES) return;
    const float* xp = x + (size_t)base * F_IN;
    float acc[8] = {0.f, 0.f, 0.f, 0.f, 0.f, 0.f, 0.f, 0.f};
#pragma unroll 4
    for (int k = 0; k < F_IN; ++k) {
        float w = Ws[k * HID + lane];
#pragma unroll
        for (int m = 0; m < 8; ++m)
            acc[m] += xp[(size_t)m * F_IN + k] * w;
    }
#pragma unroll
    for (int m = 0; m < 8; ++m) {
        int n = base + m;
        if (n < N_NODES)
            hxs[(size_t)n * HID + lane] = acc[m] * dis[n];
    }
}

// ---------------- layer-1 aggregate: gather over CSR, one wave per node
// h1[n] = dis[n] * (hxs[n] + sum_{s in in(n)} hxs[s])
__global__ __launch_bounds__(256) void k_agg1(const int* __restrict__ row_start,
                                              const int* __restrict__ csr,
                                              const float* __restrict__ dis,
                                              const float* __restrict__ hxs,
                                              float* __restrict__ h1) {
    int lane = threadIdx.x & 63;
    int node = (blockIdx.x * blockDim.x + threadIdx.x) >> 6;
    if (node >= N_NODES) return;
    int beg = row_start[node], end = row_start[node + 1];
    float acc = hxs[(size_t)node * HID + lane];
    int j = beg;
    for (; j + 4 <= end; j += 4) {
        int s0 = csr[j], s1 = csr[j + 1], s2 = csr[j + 2], s3 = csr[j + 3];
        acc += hxs[(size_t)s0 * HID + lane];
        acc += hxs[(size_t)s1 * HID + lane];
        acc += hxs[(size_t)s2 * HID + lane];
        acc += hxs[(size_t)s3 * HID + lane];
    }
    for (; j < end; ++j)
        acc += hxs[(size_t)csr[j] * HID + lane];
    h1[(size_t)node * HID + lane] = acc * dis[node];
}

// ---------------- h2s = (relu(h1 + b1) @ W2) * dis[n]
__global__ __launch_bounds__(256) void k_h2x(const float* __restrict__ h1,
                                             const float* __restrict__ b1,
                                             const float* __restrict__ W2,
                                             const float* __restrict__ dis,
                                             float* __restrict__ h2s) {
    __shared__ float W2s[HID * NC];
    __shared__ float b1s[HID];
    for (int i = threadIdx.x; i < HID * NC; i += 256) W2s[i] = W2[i];
    if (threadIdx.x < HID) b1s[threadIdx.x] = b1[threadIdx.x];
    __syncthreads();
    int c  = threadIdx.x & 15;   // 16 lanes per row, 10 active
    int rg = threadIdx.x >> 4;   // 16 rows per block
    int n  = blockIdx.x * 16 + rg;
    if (n >= N_NODES || c >= NC) return;
    const float* hr = h1 + (size_t)n * HID;
    float acc = 0.f;
#pragma unroll
    for (int k = 0; k < HID; ++k) {
        float v = hr[k] + b1s[k];
        v = v > 0.f ? v : 0.f;
        acc += v * W2s[k * NC + c];
    }
    h2s[(size_t)n * NC + c] = acc * dis[n];
}

// ---------------- layer-2 aggregate + bias + log_softmax, fused
__global__ __launch_bounds__(256) void k_agg2f(const int* __restrict__ row_start,
                                               const int* __restrict__ csr,
                                               const float* __restrict__ dis,
                                               const float* __restrict__ h2s,
                                               const float* __restrict__ b2,
                                               float* __restrict__ out) {
    int c = threadIdx.x & 15;  // 16 lanes per node, 10 active
    int node = (blockIdx.x * blockDim.x + threadIdx.x) >> 4;
    if (node >= N_NODES) return;
    int beg = row_start[node], end = row_start[node + 1];
    float acc;
    if (c < NC) {
        acc = h2s[(size_t)node * NC + c];
        int j = beg;
        for (; j + 2 <= end; j += 2) {
            int s0 = csr[j], s1 = csr[j + 1];
            acc += h2s[(size_t)s0 * NC + c];
            acc += h2s[(size_t)s1 * NC + c];
        }
        for (; j < end; ++j)
            acc += h2s[(size_t)csr[j] * NC + c];
        acc = acc * dis[node] + b2[c];
    } else {
        acc = -1e30f;
    }
    float m = acc;
#pragma unroll
    for (int off = 8; off >= 1; off >>= 1)
        m = fmaxf(m, __shfl_xor(m, off, 16));
    float e = (c < NC) ? expf(acc - m) : 0.f;
    float ssum = e;
#pragma unroll
    for (int off = 8; off >= 1; off >>= 1)
        ssum += __shfl_xor(ssum, off, 16);
    float lse = m + logf(ssum);
    if (c < NC) out[(size_t)node * NC + c] = acc - lse;
}

extern "C" void kernel_launch(void* const* d_in, const int* in_sizes, int n_in,
                              void* d_out, int out_size, void* d_ws, size_t ws_size,
                              hipStream_t stream) {
    const float* x  = (const float*)d_in[0];
    const int*   ei = (const int*)d_in[1];    // [2, E] int32 (JAX x64 off)
    const float* W1 = (const float*)d_in[2];
    const float* b1 = (const float*)d_in[3];
    const float* W2 = (const float*)d_in[4];
    const float* b2 = (const float*)d_in[5];
    float* out = (float*)d_out;

    const int* src = ei;             // edge_index[0]
    const int* dst = ei + N_EDGES;   // edge_index[1]

    char* ws = (char*)d_ws;
    size_t off = 0;
    unsigned* deg = (unsigned*)(ws + off); off += 4u * N_NODES;          // 0.4 MB
    float* dis = (float*)(ws + off);       off += 4u * N_NODES;          // 0.4 MB
    int* row_start = (int*)(ws + off);     off += 4u * (N_NODES + 4);    // 0.4 MB
    int* cursor = (int*)(ws + off);        off += 4u * N_NODES;          // 0.4 MB
    int* bsum = (int*)(ws + off);          off += 4u * RED_B;
    int* boff = (int*)(ws + off);          off += 4u * RED_B;
    int* csr = (int*)(ws + off);           off += 4u * N_EDGES;          // 6.4 MB
    float* hxs = (float*)(ws + off);       off += 4u * (size_t)N_NODES * HID;  // 25.6 MB
    float* h1  = (float*)(ws + off);       off += 4u * (size_t)N_NODES * HID;  // 25.6 MB
    float* h2s = hxs;  // hxs dead after k_agg1; reuse region (4 MB)

    hipMemsetAsync(deg, 0, 4u * N_NODES, stream);
    k_deg<<<2048, 256, 0, stream>>>(dst, deg);
    k_red<<<RED_B, 256, 0, stream>>>(deg, bsum);
    k_mid<<<1, 256, 0, stream>>>(bsum, boff);
    k_fin<<<RED_B, 256, 0, stream>>>(deg, boff, row_start, cursor, dis);
    k_fill<<<2048, 256, 0, stream>>>(src, dst, cursor, csr);
    k_xw<<<(N_NODES + 31) / 32, 256, 0, stream>>>(x, W1, dis, hxs);
    k_agg1<<<(N_NODES * 64) / 256, 256, 0, stream>>>(row_start, csr, dis, hxs, h1);
    k_h2x<<<(N_NODES + 15) / 16, 256, 0, stream>>>(h1, b1, W2, dis, h2s);
    k_agg2f<<<(N_NODES * 16) / 256, 256, 0, stream>>>(row_start, csr, dis, h2s, b2, out);
}

// Round 4
// 262.086 us; speedup vs baseline: 2.6910x; 1.5261x over previous
//
#include <hip/hip_runtime.h>
#include <hip/hip_bf16.h>

#define N_NODES 100000
#define N_EDGES 1600000
#define F_IN 128
#define HID 64
#define NC 10

#define BSH 7
#define BNODES 128                       // nodes per bucket = 1<<BSH
#define NB 782                           // ceil(N_NODES / 128)
#define PBLK 256                         // partition blocks
#define TILE ((N_EDGES + PBLK - 1) / PBLK)  // 6250 edges per block

// ---------------- s1: global bucket histogram via LDS privatization
__global__ __launch_bounds__(256) void s1_bhist(const int* __restrict__ dst,
                                                int* __restrict__ bcount) {
    __shared__ int lh[NB];
    int t = threadIdx.x;
    for (int k = t; k < NB; k += 256) lh[k] = 0;
    __syncthreads();
    int b0 = blockIdx.x * TILE;
    int b1 = b0 + TILE < N_EDGES ? b0 + TILE : N_EDGES;
    for (int i = b0 + t; i < b1; i += 256)
        atomicAdd(&lh[dst[i] >> BSH], 1);
    __syncthreads();
    for (int k = t; k < NB; k += 256) {
        int c = lh[k];
        if (c) atomicAdd(&bcount[k], c);   // coalesced across lanes
    }
}

// ---------------- s2: exclusive scan of 782 bucket counts (1 block of 1024)
__global__ __launch_bounds__(1024) void s2_bscan(const int* __restrict__ bcount,
                                                 int* __restrict__ boffset,
                                                 int* __restrict__ bcursor,
                                                 int* __restrict__ row_start) {
    __shared__ int sm[1024];
    int t = threadIdx.x;
    int v = (t < NB) ? bcount[t] : 0;
    sm[t] = v;
    __syncthreads();
    for (int off = 1; off < 1024; off <<= 1) {
        int u = (t >= off) ? sm[t - off] : 0;
        __syncthreads();
        sm[t] += u;
        __syncthreads();
    }
    int excl = sm[t] - v;
    if (t < NB) {
        boffset[t] = excl;
        bcursor[t] = excl;
    }
    if (t == NB - 1) {
        boffset[NB] = sm[t];              // == N_EDGES
        row_start[N_NODES] = sm[t];       // sentinel
    }
}

// ---------------- s3: partition edges into bucket regions (block-reserved runs)
__global__ __launch_bounds__(256) void s3_part(const int* __restrict__ src,
                                               const int* __restrict__ dst,
                                               int* __restrict__ bcursor,
                                               int2* __restrict__ ppair) {
    __shared__ int lh[NB];     // histogram, then running cursor
    __shared__ int lbase[NB];  // reserved base per bucket
    int t = threadIdx.x;
    for (int k = t; k < NB; k += 256) lh[k] = 0;
    __syncthreads();
    int b0 = blockIdx.x * TILE;
    int b1 = b0 + TILE < N_EDGES ? b0 + TILE : N_EDGES;
    for (int i = b0 + t; i < b1; i += 256)
        atomicAdd(&lh[dst[i] >> BSH], 1);
    __syncthreads();
    for (int k = t; k < NB; k += 256) {
        int c = lh[k];
        lbase[k] = c ? atomicAdd(&bcursor[k], c) : 0;  // coalesced, with return
    }
    __syncthreads();
    for (int k = t; k < NB; k += 256) lh[k] = lbase[k];
    __syncthreads();
    for (int i = b0 + t; i < b1; i += 256) {
        int d = dst[i];
        int slot = atomicAdd(&lh[d >> BSH], 1);        // LDS atomic (fast)
        ppair[slot] = make_int2(src[i], d);
    }
}

// ---------------- s4: per-bucket CSR finalize (row_start, dis, csr)
__global__ __launch_bounds__(256) void s4_build(const int2* __restrict__ ppair,
                                                const int* __restrict__ boffset,
                                                int* __restrict__ row_start,
                                                float* __restrict__ dis,
                                                int* __restrict__ csr) {
    __shared__ int h[BNODES];
    __shared__ int sc[BNODES];
    __shared__ int lcur[BNODES];
    int t = threadIdx.x;
    int b = blockIdx.x;
    int base = boffset[b];
    int cnt = boffset[b + 1] - base;
    int nodes0 = b << BSH;
    if (t < BNODES) h[t] = 0;
    __syncthreads();
    for (int j = t; j < cnt; j += 256)
        atomicAdd(&h[ppair[base + j].y - nodes0], 1);
    __syncthreads();
    // exclusive scan of h[0..127] (whole block participates in barriers)
    if (t < BNODES) sc[t] = h[t];
    __syncthreads();
    for (int off = 1; off < BNODES; off <<= 1) {
        int u = (t < BNODES && t >= off) ? sc[t - off] : 0;
        __syncthreads();
        if (t < BNODES) sc[t] += u;
        __syncthreads();
    }
    if (t < BNODES) {
        int node = nodes0 + t;
        int excl = sc[t] - h[t];
        if (node < N_NODES) {
            row_start[node] = base + excl;
            dis[node] = rsqrtf((float)(h[t] + 1));
            lcur[t] = base + excl;
        }
    }
    __syncthreads();
    for (int j = t; j < cnt; j += 256) {
        int2 p = ppair[base + j];
        int slot = atomicAdd(&lcur[p.y - nodes0], 1);   // LDS atomic
        csr[slot] = p.x;
    }
}

// ---------------- hxs = (x @ W1) * dis ; 8 nodes per wave
__global__ __launch_bounds__(256) void k_xw(const float* __restrict__ x,
                                            const float* __restrict__ W1,
                                            const float* __restrict__ dis,
                                            float* __restrict__ hxs) {
    __shared__ float Ws[F_IN * HID];  // 32 KB
    for (int i = threadIdx.x; i < F_IN * HID; i += 256) Ws[i] = W1[i];
    __syncthreads();
    int lane = threadIdx.x & 63;
    int wv = __builtin_amdgcn_readfirstlane(threadIdx.x >> 6);  // wave-uniform
    int base = (blockIdx.x * 4 + wv) * 8;  // 8 nodes per wave, 32 per block
    if (base >= N_NODES) return;
    const float* xp = x + (size_t)base * F_IN;
    float acc[8] = {0.f, 0.f, 0.f, 0.f, 0.f, 0.f, 0.f, 0.f};
#pragma unroll 4
    for (int k = 0; k < F_IN; ++k) {
        float w = Ws[k * HID + lane];
#pragma unroll
        for (int m = 0; m < 8; ++m)
            acc[m] += xp[(size_t)m * F_IN + k] * w;
    }
#pragma unroll
    for (int m = 0; m < 8; ++m) {
        int n = base + m;
        if (n < N_NODES)
            hxs[(size_t)n * HID + lane] = acc[m] * dis[n];
    }
}

// ---------------- layer-1 aggregate: gather over CSR, one wave per node
__global__ __launch_bounds__(256) void k_agg1(const int* __restrict__ row_start,
                                              const int* __restrict__ csr,
                                              const float* __restrict__ dis,
                                              const float* __restrict__ hxs,
                                              float* __restrict__ h1) {
    int lane = threadIdx.x & 63;
    int node = (blockIdx.x * blockDim.x + threadIdx.x) >> 6;
    if (node >= N_NODES) return;
    int beg = row_start[node], end = row_start[node + 1];
    float acc = hxs[(size_t)node * HID + lane];
    int j = beg;
    for (; j + 4 <= end; j += 4) {
        int s0 = csr[j], s1 = csr[j + 1], s2 = csr[j + 2], s3 = csr[j + 3];
        acc += hxs[(size_t)s0 * HID + lane];
        acc += hxs[(size_t)s1 * HID + lane];
        acc += hxs[(size_t)s2 * HID + lane];
        acc += hxs[(size_t)s3 * HID + lane];
    }
    for (; j < end; ++j)
        acc += hxs[(size_t)csr[j] * HID + lane];
    h1[(size_t)node * HID + lane] = acc * dis[node];
}

// ---------------- h2s = (relu(h1 + b1) @ W2) * dis[n]
__global__ __launch_bounds__(256) void k_h2x(const float* __restrict__ h1,
                                             const float* __restrict__ b1,
                                             const float* __restrict__ W2,
                                             const float* __restrict__ dis,
                                             float* __restrict__ h2s) {
    __shared__ float W2s[HID * NC];
    __shared__ float b1s[HID];
    for (int i = threadIdx.x; i < HID * NC; i += 256) W2s[i] = W2[i];
    if (threadIdx.x < HID) b1s[threadIdx.x] = b1[threadIdx.x];
    __syncthreads();
    int c  = threadIdx.x & 15;   // 16 lanes per row, 10 active
    int rg = threadIdx.x >> 4;   // 16 rows per block
    int n  = blockIdx.x * 16 + rg;
    if (n >= N_NODES || c >= NC) return;
    const float* hr = h1 + (size_t)n * HID;
    float acc = 0.f;
#pragma unroll
    for (int k = 0; k < HID; ++k) {
        float v = hr[k] + b1s[k];
        v = v > 0.f ? v : 0.f;
        acc += v * W2s[k * NC + c];
    }
    h2s[(size_t)n * NC + c] = acc * dis[n];
}

// ---------------- layer-2 aggregate + bias + log_softmax, fused
__global__ __launch_bounds__(256) void k_agg2f(const int* __restrict__ row_start,
                                               const int* __restrict__ csr,
                                               const float* __restrict__ dis,
                                               const float* __restrict__ h2s,
                                               const float* __restrict__ b2,
                                               float* __restrict__ out) {
    int c = threadIdx.x & 15;  // 16 lanes per node, 10 active
    int node = (blockIdx.x * blockDim.x + threadIdx.x) >> 4;
    if (node >= N_NODES) return;
    int beg = row_start[node], end = row_start[node + 1];
    float acc;
    if (c < NC) {
        acc = h2s[(size_t)node * NC + c];
        int j = beg;
        for (; j + 2 <= end; j += 2) {
            int s0 = csr[j], s1 = csr[j + 1];
            acc += h2s[(size_t)s0 * NC + c];
            acc += h2s[(size_t)s1 * NC + c];
        }
        for (; j < end; ++j)
            acc += h2s[(size_t)csr[j] * NC + c];
        acc = acc * dis[node] + b2[c];
    } else {
        acc = -1e30f;
    }
    float m = acc;
#pragma unroll
    for (int off = 8; off >= 1; off >>= 1)
        m = fmaxf(m, __shfl_xor(m, off, 16));
    float e = (c < NC) ? expf(acc - m) : 0.f;
    float ssum = e;
#pragma unroll
    for (int off = 8; off >= 1; off >>= 1)
        ssum += __shfl_xor(ssum, off, 16);
    float lse = m + logf(ssum);
    if (c < NC) out[(size_t)node * NC + c] = acc - lse;
}

static inline size_t align16(size_t v) { return (v + 15) & ~(size_t)15; }

extern "C" void kernel_launch(void* const* d_in, const int* in_sizes, int n_in,
                              void* d_out, int out_size, void* d_ws, size_t ws_size,
                              hipStream_t stream) {
    const float* x  = (const float*)d_in[0];
    const int*   ei = (const int*)d_in[1];    // [2, E] int32 (JAX x64 off)
    const float* W1 = (const float*)d_in[2];
    const float* b1 = (const float*)d_in[3];
    const float* W2 = (const float*)d_in[4];
    const float* b2 = (const float*)d_in[5];
    float* out = (float*)d_out;

    const int* src = ei;             // edge_index[0]
    const int* dst = ei + N_EDGES;   // edge_index[1]

    char* ws = (char*)d_ws;
    size_t off = 0;
    int* bcount = (int*)(ws + off);     off = align16(off + 4u * NB);
    int* boffset = (int*)(ws + off);    off = align16(off + 4u * (NB + 1));
    int* bcursor = (int*)(ws + off);    off = align16(off + 4u * NB);
    int* row_start = (int*)(ws + off);  off = align16(off + 4u * (N_NODES + 1));
    float* dis = (float*)(ws + off);    off = align16(off + 4u * N_NODES);
    int* csr = (int*)(ws + off);        off = align16(off + 4u * N_EDGES);
    float* hxs = (float*)(ws + off);    off = align16(off + 4u * (size_t)N_NODES * HID);
    float* h1  = (float*)(ws + off);    off = align16(off + 4u * (size_t)N_NODES * HID);
    int2* ppair = (int2*)h1;            // alias: h1 not written until k_agg1
    float* h2s = hxs;                   // alias: hxs dead after k_agg1

    hipMemsetAsync(bcount, 0, 4u * NB, stream);
    s1_bhist<<<PBLK, 256, 0, stream>>>(dst, bcount);
    s2_bscan<<<1, 1024, 0, stream>>>(bcount, boffset, bcursor, row_start);
    s3_part<<<PBLK, 256, 0, stream>>>(src, dst, bcursor, ppair);
    s4_build<<<NB, 256, 0, stream>>>(ppair, boffset, row_start, dis, csr);
    k_xw<<<(N_NODES + 31) / 32, 256, 0, stream>>>(x, W1, dis, hxs);
    k_agg1<<<(N_NODES * 64) / 256, 256, 0, stream>>>(row_start, csr, dis, hxs, h1);
    k_h2x<<<(N_NODES + 15) / 16, 256, 0, stream>>>(h1, b1, W2, dis, h2s);
    k_agg2f<<<(N_NODES * 16) / 256, 256, 0, stream>>>(row_start, csr, dis, h2s, b2, out);
}